// Round 8
// baseline (213.723 us; speedup 1.0000x reference)
//
#include <hip/hip_runtime.h>
#include <hip/hip_bf16.h>
#include <cfloat>
#include <math.h>

#define N_TOK   32768
#define S_CODES 1024
#define C_DIM   256

typedef __attribute__((ext_vector_type(8))) short short8v;
typedef __attribute__((ext_vector_type(4))) float float4v;

// ---- workspace byte offsets ----
#define WS_HIST 0                       // 1024 int
#define WS_LOSS 4096                    // 1 float
#define WS_W2   4608                    // 1024 float
#define WS_WHP  16384                   // w hi frags [8 kc][1024 code][4 quad][8 bf16] = 512 KB
#define WS_WLP  (WS_WHP + 524288)       // w lo frags, same layout
#define WS_NEED ((size_t)(WS_WLP + 524288))

__device__ __forceinline__ unsigned short f2bf(float f) {
    __hip_bfloat16 h = __float2bfloat16(f);
    return __builtin_bit_cast(unsigned short, h);
}
__device__ __forceinline__ float bf2f(unsigned short u) {
    return __bfloat162float(__builtin_bit_cast(__hip_bfloat16, u));
}

// ---- split w into MFMA-B-fragment-ordered hi/lo + w2; zero hist/loss ----
// grid 512 x 256: block handles 2 codes (tid>>7), thread handles k, k+1 (k=2*(tid&127))
__global__ void split_w(const float* __restrict__ w, unsigned short* __restrict__ whp,
                        unsigned short* __restrict__ wlp, float* __restrict__ w2,
                        int* __restrict__ hist, float* __restrict__ lossp) {
    __shared__ float wred[4];
    const int bid = blockIdx.x, tid = threadIdx.x;
    const int l = tid & 63, wv = tid >> 6;
    int c = 2 * bid + (tid >> 7);
    int k = (tid & 127) * 2;
    float2 v = *(const float2*)&w[(size_t)c * C_DIM + k];
    unsigned short h0 = f2bf(v.x), h1 = f2bf(v.y);
    unsigned short lo0 = f2bf(v.x - bf2f(h0)), lo1 = f2bf(v.y - bf2f(h1));
    int kc = k >> 5, qd = (k >> 3) & 3, jj = k & 7;
    size_t so = ((size_t)(kc * 1024 + c) * 4 + qd) * 8 + jj;
    *(unsigned int*)&whp[so] = (unsigned int)h0 | ((unsigned int)h1 << 16);
    *(unsigned int*)&wlp[so] = (unsigned int)lo0 | ((unsigned int)lo1 << 16);
    float s2 = v.x * v.x + v.y * v.y;
#pragma unroll
    for (int off = 32; off > 0; off >>= 1) s2 += __shfl_down(s2, off);
    if (l == 0) wred[wv] = s2;
    __syncthreads();
    if (tid == 0)   w2[c] = wred[0] + wred[1];
    if (tid == 128) w2[c] = wred[2] + wred[3];
    if (bid < 4) hist[bid * 256 + tid] = 0;       // plain-store zero (proven round 4)
    if (bid == 4 && tid == 0) *lossp = 0.f;
}

// ---- main: convert x once to LDS hi/lo, MFMA vs all 1024 codes with
//      register-direct B frags from L2 (double-buffered, no K-loop barriers),
//      argmin, hist/loss atomics, gather + out-write ----
// grid 512 blocks of 64 tokens; 256 thr; LDS 74240 -> 2 blocks/CU
__global__ void __launch_bounds__(256, 2)
vq_fused(const float* __restrict__ x, const float* __restrict__ emb,
         const unsigned short* __restrict__ whp, const unsigned short* __restrict__ wlp,
         const float* __restrict__ w2g, float* __restrict__ out,
         int* __restrict__ hist, float* __restrict__ lossp) {
    __shared__ __align__(16) char smem[74240];
    unsigned short* xh = (unsigned short*)smem;           // [64 tok][256 k] bf16 hi, 32 KB
    unsigned short* xl = (unsigned short*)(smem + 32768); // lo, 32 KB
    char* sc = smem + 65536;                              // 8704 B scratch (multi-use)

    const int tid = threadIdx.x;
    const int l = tid & 63, wv = tid >> 6;
    const int quad = l >> 4, lr = l & 15;
    const int bid = blockIdx.x;
    const int t0 = bid * 64;
    const int b = t0 >> 10, hw0 = t0 & 1023;
    const size_t xbase = ((size_t)b << 18) + hw0;         // b*256*1024 + hw0

    // ---- phase 1: stage + convert x once ----
    float x2tok = 0.f;                      // valid for tid<64 (token = tid)
    {
        float* xf32 = (float*)sc;           // [32][68] padded
        const int srow = tid >> 3, scol = (tid & 7) * 8;
        const int ct = tid & 63, ckq = tid >> 6;
        float x2p = 0.f;
        for (int kc = 0; kc < 8; ++kc) {
            __syncthreads();                // sc free
            const float* gp = x + xbase + (size_t)(kc * 32 + srow) * 1024 + scol;
            float4 a0 = *(const float4*)gp;
            float4 a1 = *(const float4*)(gp + 4);
            *(float4*)&xf32[srow * 68 + scol] = a0;
            *(float4*)&xf32[srow * 68 + scol + 4] = a1;
            __syncthreads();                // xf32 ready
            short8v hv, lv;
#pragma unroll
            for (int j2 = 0; j2 < 8; ++j2) {
                float v = xf32[(ckq * 8 + j2) * 68 + ct];
                unsigned short h = f2bf(v);
                float hf = bf2f(h);
                unsigned short lo = f2bf(v - hf);
                hv[j2] = (short)h; lv[j2] = (short)lo;
                x2p = fmaf(v, v, x2p);
            }
            int pos = (kc * 4 + ckq) ^ (ct & 31);          // XOR swizzle, 16B chunks
            *(short8v*)&xh[ct * 256 + pos * 8] = hv;
            *(short8v*)&xl[ct * 256 + pos * 8] = lv;
        }
        __syncthreads();
        float* x2sh = (float*)sc;
        x2sh[ckq * 64 + ct] = x2p;
        __syncthreads();
        if (tid < 64)
            x2tok = x2sh[tid] + x2sh[64 + tid] + x2sh[128 + tid] + x2sh[192 + tid];
        __syncthreads();                    // sc reads done before epilogue reuse
    }

    // ---- phase 2: MFMA K-loop, B frags direct from L2, A from LDS ----
    int axor[4], aoffb[4];
#pragma unroll
    for (int i = 0; i < 4; ++i) {
        int arow = i * 16 + lr;
        aoffb[i] = arow * 512;              // bytes (row = 256 shorts)
        axor[i] = arow & 31;
    }
    const char* xhc = smem;
    const char* xlc = smem + 32768;
    const char* whc = (const char*)whp;
    const char* wlc = (const char*)wlp;

    float bval[16]; int bidx[16];
#pragma unroll
    for (int s2 = 0; s2 < 16; ++s2) { bval[s2] = FLT_MAX; bidx[s2] = 0; }

    auto loadB = [&](int s, int kc, float4 (&bh)[4], float4 (&bl)[4]) {
#pragma unroll
        for (int jt = 0; jt < 4; ++jt) {
            size_t off = (((size_t)(kc * 1024 + s * 256 + wv * 64 + jt * 16 + lr)) * 4 + quad) * 16;
            bh[jt] = *(const float4*)(whc + off);
            bl[jt] = *(const float4*)(wlc + off);
        }
    };
    auto stepf = [&](int kc, const float4 (&bh)[4], const float4 (&bl)[4], float4v (&acc)[4][4]) {
        short8v ah[4], al[4];
#pragma unroll
        for (int i = 0; i < 4; ++i) {
            int pos = ((kc * 4 + quad) ^ axor[i]) * 16;
            ah[i] = *(const short8v*)(xhc + aoffb[i] + pos);
            al[i] = *(const short8v*)(xlc + aoffb[i] + pos);
        }
#pragma unroll
        for (int i = 0; i < 4; ++i)
#pragma unroll
            for (int jt = 0; jt < 4; ++jt) {
                short8v bhs = __builtin_bit_cast(short8v, bh[jt]);
                short8v bls = __builtin_bit_cast(short8v, bl[jt]);
                acc[i][jt] = __builtin_amdgcn_mfma_f32_16x16x32_bf16(ah[i], bhs, acc[i][jt], 0, 0, 0);
                acc[i][jt] = __builtin_amdgcn_mfma_f32_16x16x32_bf16(ah[i], bls, acc[i][jt], 0, 0, 0);
                acc[i][jt] = __builtin_amdgcn_mfma_f32_16x16x32_bf16(al[i], bhs, acc[i][jt], 0, 0, 0);
            }
    };

    const float4v zacc = {0.f, 0.f, 0.f, 0.f};
    float4 bhA[4], blA[4], bhB[4], blB[4];
    loadB(0, 0, bhA, blA);
    for (int s = 0; s < 4; ++s) {
        float4v acc[4][4];
#pragma unroll
        for (int i = 0; i < 4; ++i)
#pragma unroll
            for (int jt = 0; jt < 4; ++jt) acc[i][jt] = zacc;

        for (int kc = 0; kc < 8; kc += 2) {
            loadB(s, kc + 1, bhB, blB);      // prefetch odd kc
            stepf(kc, bhA, blA, acc);
            int sn = s, kn = kc + 2;
            if (kn == 8) { kn = 0; sn = s + 1; if (sn == 4) { sn = 3; kn = 7; } }
            loadB(sn, kn, bhA, blA);         // prefetch next even kc (or next strip)
            stepf(kc + 1, bhB, blB, acc);
        }
        // fold 256-code strip into running per-token argmin
#pragma unroll
        for (int jt = 0; jt < 4; ++jt) {
            int code = s * 256 + wv * 64 + jt * 16 + lr;
            float w2c = w2g[code];
#pragma unroll
            for (int i = 0; i < 4; ++i)
#pragma unroll
                for (int rr = 0; rr < 4; ++rr) {
                    float sv = fmaf(-2.f, acc[i][jt][rr], w2c);
                    int slot = i * 4 + rr;
                    if (sv < bval[slot]) { bval[slot] = sv; bidx[slot] = code; }
                }
        }
    }

    // ---- epilogue: argmin reduce, hist/loss atomics, gather + out-write ----
    float* bestv = (float*)sc;              // [4][64]
    int*   besti = (int*)(sc + 1024);
    int*   idx_sh = (int*)(sc + 2048);
#pragma unroll
    for (int slot = 0; slot < 16; ++slot) {
        float bv = bval[slot]; int bi = bidx[slot];
#pragma unroll
        for (int off = 1; off < 16; off <<= 1) {
            float ov = __shfl_xor(bv, off);
            int   oi = __shfl_xor(bi, off);
            if (ov < bv || (ov == bv && oi < bi)) { bv = ov; bi = oi; }
        }
        if (lr == 0) {
            int tok = (slot >> 2) * 16 + quad * 4 + (slot & 3);
            bestv[wv * 64 + tok] = bv; besti[wv * 64 + tok] = bi;
        }
    }
    __syncthreads();
    if (tid < 64) {
        float bv = bestv[tid]; int bi = besti[tid];
#pragma unroll
        for (int w = 1; w < 4; ++w) {
            float ov = bestv[w * 64 + tid]; int oi = besti[w * 64 + tid];
            if (ov < bv || (ov == bv && oi < bi)) { bv = ov; bi = oi; }
        }
        idx_sh[tid] = bi;
        atomicAdd(&hist[bi], 1);            // proven rounds 1-4 (separate-kernel read)
        float lsum = bv + x2tok;            // |q-x|^2 = (w2 - 2 q.x) + x^2
#pragma unroll
        for (int off = 32; off > 0; off >>= 1) lsum += __shfl_down(lsum, off);
        if (tid == 0) atomicAdd(lossp, lsum);
    }
    __syncthreads();
    {
        int t = tid & 63, cq = tid >> 6;
        int id = idx_sh[t];
        const float* erow = emb + (size_t)id * C_DIM;
        float* ob = out + xbase + t;
#pragma unroll
        for (int cb = 0; cb < 16; ++cb) {
            int c4 = cb * 16 + cq * 4;
            float4 q4 = *(const float4*)&erow[c4];
            ob[(size_t)(c4 + 0) * 1024] = q4.x;
            ob[(size_t)(c4 + 1) * 1024] = q4.y;
            ob[(size_t)(c4 + 2) * 1024] = q4.z;
            ob[(size_t)(c4 + 3) * 1024] = q4.w;
        }
    }
}

__global__ void finalize_kernel(const int* __restrict__ hist, const float* __restrict__ lossp,
                                float* __restrict__ out) {
    __shared__ float red[16];
    int tid = threadIdx.x;                  // 1024 threads
    float p = (float)hist[tid] * (1.f / 32768.f);
    float term = p * logf(p + 1e-6f);
#pragma unroll
    for (int off = 32; off > 0; off >>= 1) term += __shfl_down(term, off);
    if ((tid & 63) == 0) red[tid >> 6] = term;
    __syncthreads();
    if (tid == 0) {
        float s = 0.f;
#pragma unroll
        for (int i = 0; i < 16; ++i) s += red[i];
        out[8388608] = 0.25f * lossp[0] * (1.f / 8388608.f);   // quant_loss
        out[8388609] = expf(-s);                               // perplexity
    }
}

// ======== fallback path (round-1 kernels, known-correct) if ws too small ========
__global__ void w2_kernel(const float* __restrict__ w, float* __restrict__ w2) {
    int code = blockIdx.x * blockDim.x + threadIdx.x;
    const float4* r = (const float4*)(w + (size_t)code * C_DIM);
    float s = 0.f;
#pragma unroll 8
    for (int i = 0; i < C_DIM / 4; ++i) {
        float4 v = r[i];
        s += v.x * v.x + v.y * v.y + v.z * v.z + v.w * v.w;
    }
    w2[code] = s;
}

__launch_bounds__(256, 2)
__global__ void vq_main(const float* __restrict__ x, const float* __restrict__ emb,
                        float* __restrict__ out, int* __restrict__ hist,
                        float* __restrict__ lossp, const float* __restrict__ w2) {
    __shared__ float w_lds[8 * S_CODES];
    __shared__ float x_lds[C_DIM * 32];
    const int tid = threadIdx.x;
    const int l = tid & 63, wv = tid >> 6;
    const int t0 = blockIdx.x * 32;
    const int b = t0 >> 10, hw0 = t0 & 1023;
    const float* xbase = x + ((size_t)b * C_DIM << 10) + hw0;
    {
        int rl = tid & 7, r0 = tid >> 3;
        for (int rep = 0; rep < 8; ++rep) {
            int c = rep * 32 + r0;
            float4 v = *(const float4*)(xbase + ((size_t)c << 10) + rl * 4);
            *(float4*)&x_lds[c * 32 + rl * 4] = v;
        }
    }
    float4 pre[8];
#pragma unroll
    for (int m = 0; m < 8; ++m) {
        int fid = m * 256 + tid;
        int code = fid >> 1, kq = fid & 1;
        pre[m] = *(const float4*)(emb + (size_t)code * C_DIM + kq * 4);
    }
    float acc[8][16];
#pragma unroll
    for (int t = 0; t < 8; ++t)
#pragma unroll
        for (int j = 0; j < 16; ++j) acc[t][j] = 0.f;
    __syncthreads();
    for (int chunk = 0; chunk < 32; ++chunk) {
#pragma unroll
        for (int m = 0; m < 8; ++m) {
            int fid = m * 256 + tid;
            int code = fid >> 1, kq = fid & 1;
            float4 v = pre[m];
            w_lds[(kq * 4 + 0) * S_CODES + code] = v.x;
            w_lds[(kq * 4 + 1) * S_CODES + code] = v.y;
            w_lds[(kq * 4 + 2) * S_CODES + code] = v.z;
            w_lds[(kq * 4 + 3) * S_CODES + code] = v.w;
        }
        if (chunk + 1 < 32) {
            int k0n = (chunk + 1) * 8;
#pragma unroll
            for (int m = 0; m < 8; ++m) {
                int fid = m * 256 + tid;
                int code = fid >> 1, kq = fid & 1;
                pre[m] = *(const float4*)(emb + (size_t)code * C_DIM + k0n + kq * 4);
            }
        }
        __syncthreads();
        int k0 = chunk * 8;
#pragma unroll
        for (int kk = 0; kk < 8; ++kk) {
            int k = k0 + kk;
            float4 wq0 = *(const float4*)&w_lds[kk * S_CODES +   0 + l * 4];
            float4 wq1 = *(const float4*)&w_lds[kk * S_CODES + 256 + l * 4];
            float4 wq2 = *(const float4*)&w_lds[kk * S_CODES + 512 + l * 4];
            float4 wq3 = *(const float4*)&w_lds[kk * S_CODES + 768 + l * 4];
            float4 xa = *(const float4*)&x_lds[k * 32 + wv * 8];
            float4 xb = *(const float4*)&x_lds[k * 32 + wv * 8 + 4];
            float xs[8] = {xa.x, xa.y, xa.z, xa.w, xb.x, xb.y, xb.z, xb.w};
            float wvv[16] = {wq0.x, wq0.y, wq0.z, wq0.w, wq1.x, wq1.y, wq1.z, wq1.w,
                             wq2.x, wq2.y, wq2.z, wq2.w, wq3.x, wq3.y, wq3.z, wq3.w};
#pragma unroll
            for (int t = 0; t < 8; ++t) {
                float xv = xs[t];
#pragma unroll
                for (int j = 0; j < 16; ++j) acc[t][j] = fmaf(xv, wvv[j], acc[t][j]);
            }
        }
        __syncthreads();
    }
    float w2v[16];
#pragma unroll
    for (int m = 0; m < 4; ++m) {
        float4 v = *(const float4*)&w2[m * 256 + l * 4];
        w2v[m*4+0] = v.x; w2v[m*4+1] = v.y; w2v[m*4+2] = v.z; w2v[m*4+3] = v.w;
    }
    int* idx_sh = (int*)w_lds;
    float* red = (float*)(w_lds + 64);
#pragma unroll
    for (int t = 0; t < 8; ++t) {
        float bv = FLT_MAX; int bi = 0;
#pragma unroll
        for (int m = 0; m < 4; ++m)
#pragma unroll
            for (int j = 0; j < 4; ++j) {
                float s = w2v[m*4+j] - 2.f * acc[t][m*4+j];
                int c = m * 256 + l * 4 + j;
                if (s < bv) { bv = s; bi = c; }
            }
#pragma unroll
        for (int off = 32; off > 0; off >>= 1) {
            float ov = __shfl_xor(bv, off);
            int oi = __shfl_xor(bi, off);
            if (ov < bv || (ov == bv && oi < bi)) { bv = ov; bi = oi; }
        }
        if (l == 0) idx_sh[wv * 8 + t] = bi;
    }
    __syncthreads();
    if (tid < 32) atomicAdd(&hist[idx_sh[tid]], 1);
    float lsum = 0.f;
    for (int e = tid; e < C_DIM * 32; e += 256) {
        int t = e & 31, c = e >> 5;
        int id = idx_sh[t];
        float q = emb[(size_t)id * C_DIM + c];
        float xv = x_lds[c * 32 + t];
        float d = q - xv;
        lsum += d * d;
        out[((size_t)(b * C_DIM + c) << 10) + hw0 + t] = q;
    }
#pragma unroll
    for (int off = 32; off > 0; off >>= 1) lsum += __shfl_down(lsum, off);
    if (l == 0) red[wv] = lsum;
    __syncthreads();
    if (tid == 0) atomicAdd(lossp, red[0] + red[1] + red[2] + red[3]);
}

extern "C" void kernel_launch(void* const* d_in, const int* in_sizes, int n_in,
                              void* d_out, int out_size, void* d_ws, size_t ws_size,
                              hipStream_t stream) {
    const float* x   = (const float*)d_in[0];
    const float* emb = (const float*)d_in[1];
    float* out = (float*)d_out;
    char* ws = (char*)d_ws;
    int*   hist  = (int*)(ws + WS_HIST);
    float* lossp = (float*)(ws + WS_LOSS);
    float* w2    = (float*)(ws + WS_W2);

    if (ws_size >= WS_NEED) {
        unsigned short* whp = (unsigned short*)(ws + WS_WHP);
        unsigned short* wlp = (unsigned short*)(ws + WS_WLP);
        split_w<<<512, 256, 0, stream>>>(emb, whp, wlp, w2, hist, lossp);
        vq_fused<<<512, 256, 0, stream>>>(x, emb, whp, wlp, w2, out, hist, lossp);
    } else {
        hipMemsetAsync(d_ws, 0, 4608, stream);
        w2_kernel<<<4, 256, 0, stream>>>(emb, w2);
        vq_main<<<1024, 256, 0, stream>>>(x, emb, out, hist, lossp, w2);
    }
    finalize_kernel<<<1, 1024, 0, stream>>>(hist, lossp, out);
}